// Round 1
// baseline (332.358 us; speedup 1.0000x reference)
//
#include <hip/hip_runtime.h>

// GAE backward scan: B=8192 rows, S=2048 steps, fp32.
// One wave (64 lanes) per row; each lane owns 32 contiguous timesteps.
// Segmented parallel scan of the affine recurrence g_t = a_t*g_{t+1} + b_t.

static constexpr int BATCH = 8192;
static constexpr int SEQ   = 2048;
static constexpr int CHUNK = SEQ / 64;          // 32 elements per lane
static constexpr float GAMMA  = 0.999f;
static constexpr float LAMBDA = 0.95f;
static constexpr float GL     = GAMMA * LAMBDA; // 0.94905f

__global__ __launch_bounds__(256, 2) void gae_kernel(
    const float* __restrict__ rewards,
    const float* __restrict__ values,
    const int*   __restrict__ dones,
    const int*   __restrict__ mask,
    float*       __restrict__ out)   // [2*B*S]: advantages then returns
{
    const int lane = threadIdx.x & 63;
    const int row  = blockIdx.x * (blockDim.x >> 6) + (threadIdx.x >> 6);
    if (row >= BATCH) return;

    const size_t base = (size_t)row * SEQ + (size_t)lane * CHUNK;

    // Per-lane state (registers): a, b of the affine map, and masked values.
    float a[CHUNK], b[CHUNK], vmm[CHUNK];

    const float4* rp = reinterpret_cast<const float4*>(rewards + base);
    const float4* vp = reinterpret_cast<const float4*>(values  + base);
    const int4*   dp = reinterpret_cast<const int4*>(dones + base);
    const int4*   mp = reinterpret_cast<const int4*>(mask  + base);

    // b[k] needs vmm[k+1]; compute b one element late via pending scalars.
    float pend_mr = 0.f, pend_mnd = 0.f, pend_vmm = 0.f;

    #pragma unroll
    for (int q = 0; q < CHUNK / 4; ++q) {
        float4 r4 = rp[q];
        float4 v4 = vp[q];
        int4   d4 = dp[q];
        int4   m4 = mp[q];
        float rr[4]  = {r4.x, r4.y, r4.z, r4.w};
        float vv[4]  = {v4.x, v4.y, v4.z, v4.w};
        float dd[4]  = {(float)d4.x, (float)d4.y, (float)d4.z, (float)d4.w};
        float mm[4]  = {(float)m4.x, (float)m4.y, (float)m4.z, (float)m4.w};
        #pragma unroll
        for (int j = 0; j < 4; ++j) {
            const int k = 4 * q + j;
            const float m   = mm[j];
            const float nd  = 1.0f - dd[j];
            const float mnd = m * nd;
            vmm[k] = m * vv[j];
            a[k]   = GL * mnd;
            if (k > 0) {
                // b[k-1] = m*r + GAMMA * (m[k]*v[k]) * (m*nd) - m*v  (nv is masked next value)
                b[k - 1] = pend_mr + GAMMA * vmm[k] * pend_mnd - pend_vmm;
            }
            pend_mr  = m * rr[j];
            pend_mnd = mnd;
            pend_vmm = vmm[k];
        }
    }
    // Last element of this lane's chunk: next value is the NEXT lane's vmm[0];
    // lane 63 owns t=S-1 whose next value is 0.
    float nv_edge = __shfl_down(vmm[0], 1, 64);
    if (lane == 63) nv_edge = 0.0f;
    b[CHUNK - 1] = pend_mr + GAMMA * nv_edge * pend_mnd - pend_vmm;

    // Local (reverse-time) composition over this lane's chunk:
    // F = f_{t0} ∘ ... ∘ f_{t0+CHUNK-1}, F(g) = A*g + B.
    float A = 1.0f, Bc = 0.0f;
    #pragma unroll
    for (int k = CHUNK - 1; k >= 0; --k) {
        Bc = fmaf(a[k], Bc, b[k]);
        A  = a[k] * A;
    }

    // Wave-level inclusive suffix scan of compositions (lane i ends with
    // composition over lanes [i, 64)). Combine: F_i = F_i ∘ F_{i+d}.
    #pragma unroll
    for (int d = 1; d < 64; d <<= 1) {
        float Ao = __shfl_down(A,  d, 64);
        float Bo = __shfl_down(Bc, d, 64);
        if (lane + d < 64) {
            Bc = fmaf(A, Bo, Bc);
            A  = A * Ao;
        }
    }
    // Carry entering this lane's chunk = suffix over lanes (i, 64) applied to
    // g_S = 0, i.e. the B of lane i+1's scan result. Lane 63 carries 0.
    float carry = __shfl_down(Bc, 1, 64);
    if (lane == 63) carry = 0.0f;

    // Apply recurrence; overwrite b[] with advantages, vmm[] with returns.
    float g = carry;
    #pragma unroll
    for (int k = CHUNK - 1; k >= 0; --k) {
        g = fmaf(a[k], g, b[k]);
        b[k]   = g;            // advantage (already 0 outside valid prefix)
        vmm[k] = vmm[k] + g;   // return = g + mask*v (0 outside prefix)
    }

    float4* ap = reinterpret_cast<float4*>(out + base);
    float4* tp = reinterpret_cast<float4*>(out + (size_t)BATCH * SEQ + base);
    #pragma unroll
    for (int q = 0; q < CHUNK / 4; ++q) {
        ap[q] = make_float4(b[4*q+0],   b[4*q+1],   b[4*q+2],   b[4*q+3]);
        tp[q] = make_float4(vmm[4*q+0], vmm[4*q+1], vmm[4*q+2], vmm[4*q+3]);
    }
}

extern "C" void kernel_launch(void* const* d_in, const int* in_sizes, int n_in,
                              void* d_out, int out_size, void* d_ws, size_t ws_size,
                              hipStream_t stream) {
    const float* rewards = (const float*)d_in[0];
    const float* values  = (const float*)d_in[1];
    const int*   dones   = (const int*)d_in[2];
    const int*   mask    = (const int*)d_in[3];
    float* out = (float*)d_out;

    const int rows_per_block = 256 / 64;                 // 4 waves -> 4 rows
    dim3 grid(BATCH / rows_per_block), block(256);
    gae_kernel<<<grid, block, 0, stream>>>(rewards, values, dones, mask, out);
}